// Round 14
// baseline (3893.863 us; speedup 1.0000x reference)
//
#include <hip/hip_runtime.h>
#include <hip/hip_bf16.h>
#include <cmath>

// Problem constants
#define BATCH 16
#define SEQ 256
#define EMBED 512
#define HIDDEN 1024
#define GATES 4096       // 4*HIDDEN
#define VOCAB 32000
#define MROWS 4096       // BATCH*SEQ
#define LOGITS_SZ 131072000  // 16*256*32000

#define NSLOT 257                    // h-history slots (init + 256 steps)
#define SEQ_SLOTU16 16384            // u16 per slot: 16 batch x 1024
#define SEQ_LOU16 (NSLOT * SEQ_SLOTU16)

typedef unsigned int u32;
typedef unsigned short u16;
typedef unsigned long long u64;
typedef __attribute__((ext_vector_type(8))) short bf16x8;
typedef __attribute__((ext_vector_type(4))) float f32x4;

#define AS1 __attribute__((address_space(1)))
#define AS3 __attribute__((address_space(3)))

// ---------------- helpers ----------------
__device__ __forceinline__ u32 f2bf(float f) {          // RNE fp32->bf16 (bits)
    u32 u = __float_as_uint(f);
    return (u + 0x7fffu + ((u >> 16) & 1u)) >> 16;
}
__device__ __forceinline__ float bf2f(u32 b) { return __uint_as_float(b << 16); }

__device__ __forceinline__ void astore(u64* p, u64 v) {
    __hip_atomic_store(p, v, __ATOMIC_RELAXED, __HIP_MEMORY_SCOPE_AGENT);
}

// ---------------- embedding gather -> bf16 hi/lo planes ----------------
__global__ void embed_hl_kernel(const int* __restrict__ x, const float* __restrict__ emb,
                                u16* __restrict__ XH, u16* __restrict__ XL) {
    int r = blockIdx.x;            // r = s*16 + b
    int s = r >> 4, b = r & 15;
    int tok = x[b * SEQ + s];
    const float4* src = (const float4*)(emb + (size_t)tok * EMBED);
    int i = threadIdx.x;           // 0..127, 4 elems each
    float4 a = src[i];
    u32 h0 = f2bf(a.x), h1 = f2bf(a.y), h2 = f2bf(a.z), h3 = f2bf(a.w);
    u64 hq = (u64)(h0 | (h1 << 16)) | ((u64)(h2 | (h3 << 16)) << 32);
    u32 l0 = f2bf(a.x - bf2f(h0)), l1 = f2bf(a.y - bf2f(h1));
    u32 l2 = f2bf(a.z - bf2f(h2)), l3 = f2bf(a.w - bf2f(h3));
    u64 lq = (u64)(l0 | (l1 << 16)) | ((u64)(l2 | (l3 << 16)) << 32);
    ((u64*)(XH + (size_t)r * EMBED))[i] = hq;
    ((u64*)(XL + (size_t)r * EMBED))[i] = lq;
}

// ---------------- fp32 -> bf16 conversion (hi only, for fc_W) ----------------
__global__ __launch_bounds__(256) void f32_to_bf16_kernel(
    const float* __restrict__ in, u16* __restrict__ out, int n8) {
    for (int i = blockIdx.x * 256 + threadIdx.x; i < n8; i += gridDim.x * 256) {
        float4 a = ((const float4*)in)[2 * (size_t)i + 0];
        float4 b = ((const float4*)in)[2 * (size_t)i + 1];
        uint4 o;
        o.x = f2bf(a.x) | (f2bf(a.y) << 16);
        o.y = f2bf(a.z) | (f2bf(a.w) << 16);
        o.z = f2bf(b.x) | (f2bf(b.y) << 16);
        o.w = f2bf(b.z) | (f2bf(b.w) << 16);
        ((uint4*)out)[i] = o;
    }
}

// ---------------- fp32 -> bf16 hi+lo split ----------------
__global__ __launch_bounds__(256) void f32_to_bf16hl_kernel(
    const float* __restrict__ in, u16* __restrict__ hi, u16* __restrict__ lo, int n4) {
    for (int i = blockIdx.x * 256 + threadIdx.x; i < n4; i += gridDim.x * 256) {
        float4 a = ((const float4*)in)[i];
        u32 h0 = f2bf(a.x), h1 = f2bf(a.y), h2 = f2bf(a.z), h3 = f2bf(a.w);
        u64 hq = (u64)(h0 | (h1 << 16)) | ((u64)(h2 | (h3 << 16)) << 32);
        u32 l0 = f2bf(a.x - bf2f(h0)), l1 = f2bf(a.y - bf2f(h1));
        u32 l2 = f2bf(a.z - bf2f(h2)), l3 = f2bf(a.w - bf2f(h3));
        u64 lq = (u64)(l0 | (l1 << 16)) | ((u64)(l2 | (l3 << 16)) << 32);
        ((u64*)hi)[i] = hq;
        ((u64*)lo)[i] = lq;
    }
}

// ---------------- W_ih1 pre-swizzle into MFMA fragment order ----------------
__global__ __launch_bounds__(256) void wih_swizzle_kernel(
    const float* __restrict__ W, u16* __restrict__ hi, u16* __restrict__ lo) {
    int bid = blockIdx.x, tid = threadIdx.x;
    int j0 = bid * 4;
#pragma unroll
    for (int i = 0; i < 8; i++) {
        int q = i * 256 + tid;           // 0..2047
        int s32 = q >> 6, l = q & 63;
        int row = l & 15, hi4 = l >> 4;
        int nrow = (row >> 2) * HIDDEN + j0 + (row & 3);
        int k = s32 * 32 + hi4 * 8;
        const float* src = W + (size_t)nrow * HIDDEN + k;
        u32 hw[4], lw[4];
#pragma unroll
        for (int e = 0; e < 4; e++) {
            float x0 = src[2 * e], x1 = src[2 * e + 1];
            u32 h0 = f2bf(x0), h1 = f2bf(x1);
            hw[e] = h0 | (h1 << 16);
            lw[e] = f2bf(x0 - bf2f(h0)) | (f2bf(x1 - bf2f(h1)) << 16);
        }
        size_t e0 = (size_t)bid * 2048 + q;
        ((uint4*)hi)[e0] = make_uint4(hw[0], hw[1], hw[2], hw[3]);
        ((uint4*)lo)[e0] = make_uint4(lw[0], lw[1], lw[2], lw[3]);
    }
}

// ---------------- split-precision MFMA input projection (layer 0) ----------
// G0[r][n] = sum_k X[r][k]*Wih0[n][k] + b1[n] + b2[n], via hi/lo 3-chain MFMA.
__global__ __launch_bounds__(256) void xproj_mfma(
    const u16* __restrict__ Ahi, const u16* __restrict__ Alo,   // [MROWS][512]
    const u16* __restrict__ Bhi, const u16* __restrict__ Blo,   // [4096][512]
    const float* __restrict__ b1, const float* __restrict__ b2,
    float* __restrict__ C) {                                    // [MROWS][4096]
    const int K = EMBED;           // 512
    const int N = GATES;
    __shared__ char smem[32768];
    char* AsH = smem;
    char* AsL = smem + 8192;
    char* BsH = smem + 16384;
    char* BsL = smem + 24576;

    int tid = threadIdx.x;
    int w = tid >> 6, l = tid & 63;
    int lin = blockIdx.y * gridDim.x + blockIdx.x;   // [0,1024)
    int swz = (lin & 7) * 128 + (lin >> 3);          // bijective XCD chunks
    int bn = swz % 32, bm = swz / 32;
    int wr = w >> 1, wc = w & 1;
    int lr = l & 15, lk = l >> 4;

    f32x4 acc[4][4];
#pragma unroll
    for (int m = 0; m < 4; m++)
#pragma unroll
        for (int n = 0; n < 4; n++) acc[m][n] = {0.f, 0.f, 0.f, 0.f};

    int srow = tid >> 2, skc = (tid & 3) * 8;
    const u16* gah0 = Ahi + (size_t)(bm * 128 + srow) * K + skc;
    const u16* gah1 = Ahi + (size_t)(bm * 128 + 64 + srow) * K + skc;
    const u16* gal0 = Alo + (size_t)(bm * 128 + srow) * K + skc;
    const u16* gal1 = Alo + (size_t)(bm * 128 + 64 + srow) * K + skc;
    const u16* gbh0 = Bhi + (size_t)(bn * 128 + srow) * K + skc;
    const u16* gbh1 = Bhi + (size_t)(bn * 128 + 64 + srow) * K + skc;
    const u16* gbl0 = Blo + (size_t)(bn * 128 + srow) * K + skc;
    const u16* gbl1 = Blo + (size_t)(bn * 128 + 64 + srow) * K + skc;
    char* lah0 = AsH + w * 1024;       char* lah1 = AsH + 4096 + w * 1024;
    char* lal0 = AsL + w * 1024;       char* lal1 = AsL + 4096 + w * 1024;
    char* lbh0 = BsH + w * 1024;       char* lbh1 = BsH + 4096 + w * 1024;
    char* lbl0 = BsL + w * 1024;       char* lbl1 = BsL + 4096 + w * 1024;

    int afo[4], bfo[4];
#pragma unroll
    for (int m = 0; m < 4; m++) afo[m] = (wr * 64 + m * 16 + lr) * 64 + lk * 16;
#pragma unroll
    for (int n = 0; n < 4; n++) bfo[n] = (wc * 64 + n * 16 + lr) * 64 + lk * 16;

    for (int k0 = 0; k0 < K; k0 += 32) {
        __syncthreads();
        __builtin_amdgcn_global_load_lds((const AS1 u32*)(const void*)(gah0 + k0),
                                         (AS3 u32*)(void*)lah0, 16, 0, 0);
        __builtin_amdgcn_global_load_lds((const AS1 u32*)(const void*)(gah1 + k0),
                                         (AS3 u32*)(void*)lah1, 16, 0, 0);
        __builtin_amdgcn_global_load_lds((const AS1 u32*)(const void*)(gal0 + k0),
                                         (AS3 u32*)(void*)lal0, 16, 0, 0);
        __builtin_amdgcn_global_load_lds((const AS1 u32*)(const void*)(gal1 + k0),
                                         (AS3 u32*)(void*)lal1, 16, 0, 0);
        __builtin_amdgcn_global_load_lds((const AS1 u32*)(const void*)(gbh0 + k0),
                                         (AS3 u32*)(void*)lbh0, 16, 0, 0);
        __builtin_amdgcn_global_load_lds((const AS1 u32*)(const void*)(gbh1 + k0),
                                         (AS3 u32*)(void*)lbh1, 16, 0, 0);
        __builtin_amdgcn_global_load_lds((const AS1 u32*)(const void*)(gbl0 + k0),
                                         (AS3 u32*)(void*)lbl0, 16, 0, 0);
        __builtin_amdgcn_global_load_lds((const AS1 u32*)(const void*)(gbl1 + k0),
                                         (AS3 u32*)(void*)lbl1, 16, 0, 0);
        __syncthreads();

        bf16x8 ah[4], al[4], bh[4], bl[4];
#pragma unroll
        for (int m = 0; m < 4; m++) {
            ah[m] = *(const bf16x8*)(AsH + afo[m]);
            al[m] = *(const bf16x8*)(AsL + afo[m]);
        }
#pragma unroll
        for (int n = 0; n < 4; n++) {
            bh[n] = *(const bf16x8*)(BsH + bfo[n]);
            bl[n] = *(const bf16x8*)(BsL + bfo[n]);
        }
#pragma unroll
        for (int m = 0; m < 4; m++)
#pragma unroll
            for (int n = 0; n < 4; n++) {
                acc[m][n] = __builtin_amdgcn_mfma_f32_16x16x32_bf16(ah[m], bh[n], acc[m][n], 0, 0, 0);
                acc[m][n] = __builtin_amdgcn_mfma_f32_16x16x32_bf16(al[m], bh[n], acc[m][n], 0, 0, 0);
                acc[m][n] = __builtin_amdgcn_mfma_f32_16x16x32_bf16(ah[m], bl[n], acc[m][n], 0, 0, 0);
            }
    }

    int rbase = bm * 128 + wr * 64 + lk * 4;
    int cbase = bn * 128 + wc * 64 + lr;
#pragma unroll
    for (int m = 0; m < 4; m++) {
#pragma unroll
        for (int n = 0; n < 4; n++) {
            int c = cbase + n * 16;
            float bb = b1[c] + b2[c];
#pragma unroll
            for (int j = 0; j < 4; j++) {
                int r = rbase + m * 16 + j;
                C[(size_t)r * N + c] = acc[m][n][j] + bb;
            }
        }
    }
}

// ---------------- bf16 MFMA FC GEMM (XCD swizzle + coalesced epilogue) -------
__global__ __launch_bounds__(256) void fc_mfma(
    const u16* __restrict__ Abf,   // [MROWS][1024] bf16
    const u16* __restrict__ Bbf,   // [VOCAB][1024] bf16
    const float* __restrict__ bias,
    float* __restrict__ C) {
    const int K = HIDDEN;
    const int N = VOCAB;
    __shared__ __align__(16) char smem[16896];   // staging 16KB; epilogue Ct 32x132 f32
    char* As = smem;
    char* Bs = smem + 8192;

    int tid = threadIdx.x;
    int w = tid >> 6, l = tid & 63;
    // XCD-aware bijective swizzle (T1): nwg = 250*32 = 8000, 8000 % 8 == 0.
    int lin = blockIdx.y * gridDim.x + blockIdx.x;
    int swz = (lin & 7) * 1000 + (lin >> 3);
    int bn = swz % 250, bm = swz / 250;
    int wr = w >> 1, wc = w & 1;
    int lr = l & 15, lk = l >> 4;

    f32x4 acc[4][4];
#pragma unroll
    for (int m = 0; m < 4; m++)
#pragma unroll
        for (int n = 0; n < 4; n++) acc[m][n] = {0.f, 0.f, 0.f, 0.f};

    int srow = tid >> 2, skc = (tid & 3) * 8;
    const u16* ga0 = Abf + (size_t)(bm * 128 + srow) * K + skc;
    const u16* ga1 = Abf + (size_t)(bm * 128 + 64 + srow) * K + skc;
    const u16* gb0 = Bbf + (size_t)(bn * 128 + srow) * K + skc;
    const u16* gb1 = Bbf + (size_t)(bn * 128 + 64 + srow) * K + skc;
    char* la0 = As + w * 1024;
    char* la1 = As + 4096 + w * 1024;
    char* lb0 = Bs + w * 1024;
    char* lb1 = Bs + 4096 + w * 1024;

    int afo[4], bfo[4];
#pragma unroll
    for (int m = 0; m < 4; m++) afo[m] = (wr * 64 + m * 16 + lr) * 64 + lk * 16;
#pragma unroll
    for (int n = 0; n < 4; n++) bfo[n] = (wc * 64 + n * 16 + lr) * 64 + lk * 16;

    for (int k0 = 0; k0 < K; k0 += 32) {
        __syncthreads();
        __builtin_amdgcn_global_load_lds((const AS1 u32*)(const void*)(ga0 + k0),
                                         (AS3 u32*)(void*)la0, 16, 0, 0);
        __builtin_amdgcn_global_load_lds((const AS1 u32*)(const void*)(ga1 + k0),
                                         (AS3 u32*)(void*)la1, 16, 0, 0);
        __builtin_amdgcn_global_load_lds((const AS1 u32*)(const void*)(gb0 + k0),
                                         (AS3 u32*)(void*)lb0, 16, 0, 0);
        __builtin_amdgcn_global_load_lds((const AS1 u32*)(const void*)(gb1 + k0),
                                         (AS3 u32*)(void*)lb1, 16, 0, 0);
        __syncthreads();

        bf16x8 af[4], bfr[4];
#pragma unroll
        for (int m = 0; m < 4; m++) af[m] = *(const bf16x8*)(As + afo[m]);
#pragma unroll
        for (int n = 0; n < 4; n++) bfr[n] = *(const bf16x8*)(Bs + bfo[n]);
#pragma unroll
        for (int m = 0; m < 4; m++)
#pragma unroll
            for (int n = 0; n < 4; n++)
                acc[m][n] = __builtin_amdgcn_mfma_f32_16x16x32_bf16(
                    af[m], bfr[n], acc[m][n], 0, 0, 0);
    }

    // ---- coalesced epilogue: per m-group (32 rows x 128 cols) via LDS ----
    // Old scattered epilogue wrote 64B runs; this stages to LDS then emits
    // 512B-contiguous runs (8 threads x 16 floats per row). Same values,
    // same destinations: r = bm*128 + (rl>>4)*64 + m*16 + (rl&15),
    // c = bn*128 + col, orow = (r&15)*SEQ + (r>>4).
    float* Ct = (float*)smem;            // [32][132] stride-132 (16B-aligned rows)
    const int erl = tid >> 3;            // writer row 0..31
    const int ecq = (tid & 7) * 16;      // writer col offset
    const int er = bm * 128 + (erl >> 4) * 64 + (erl & 15);   // + m*16 below
    const int ec0 = bn * 128 + ecq;
#pragma unroll
    for (int m = 0; m < 4; m++) {
        __syncthreads();                 // K-loop LDS reads / prev chunk done
#pragma unroll
        for (int n = 0; n < 4; n++) {
            const int col = wc * 64 + n * 16 + lr;
#pragma unroll
            for (int j = 0; j < 4; j++) {
                const int rl = wr * 16 + lk * 4 + j;
                Ct[rl * 132 + col] = acc[m][n][j];
            }
        }
        __syncthreads();
        const int r = er + m * 16;
        const int orow = (r & 15) * SEQ + (r >> 4);
        float* dst = C + (size_t)orow * N + ec0;
        const float* bp = bias + ec0;
        const float* srcl = Ct + erl * 132 + ecq;
#pragma unroll
        for (int q = 0; q < 4; q++) {
            float4 v = *(const float4*)(srcl + q * 4);
            float4 b = *(const float4*)(bp + q * 4);
            v.x += b.x; v.y += b.y; v.z += b.z; v.w += b.w;
            *(float4*)(dst + q * 4) = v;
        }
    }
}

// ---------------- fused balanced 2-layer persistent LSTM (R11-proven) --------
// 256 blocks x 256 threads. EVERY block owns 4 L0 units AND 4 L1 units.
// Step s: L0 computes t=s, L1 computes t=s-1; both consume seq0 slot s.
// Whh0/Whh1 hi/lo in LDS; W_ih1 STREAMED from L2 in pre-swizzled fragment
// order (register-resident variant miscompiles/corrupts — R10/R12 bisect;
// do NOT re-attempt). Unified wave-0 tail, single-wave vmcnt->arrive->poll.
__global__ __launch_bounds__(256, 1) void lstm_fused(
    const float* __restrict__ Whh0, const float* __restrict__ Whh1,
    const float* __restrict__ G0,        // [4096][4096] rows t*16+b (L0 x-proj + biases)
    const u16* __restrict__ wih_hi,      // pre-swizzled [256][2048] x 16B
    const u16* __restrict__ wih_lo,
    const float* __restrict__ bi1, const float* __restrict__ bh1,
    const float* __restrict__ c0in,      // [2][16][1024]
    float* __restrict__ c_tail, float* __restrict__ h_tail,  // [2][16][1024]
    u16* __restrict__ seq0, u16* __restrict__ seq1,          // [NSLOT hi | NSLOT lo]
    u32* __restrict__ arrive) {
    __shared__ __align__(16) char lds[139264];
    char* W0hi = lds;                   // [16 rows][2048B] swizzled Whh0 hi
    char* W0lo = lds + 32768;
    char* W1hi = lds + 65536;
    char* W1lo = lds + 98304;
    float* Pw = (float*)(lds + 131072); // [2 layer][4 wave][64 lane][4] = 8 KB

    const int tid = threadIdx.x;
    const int bid = blockIdx.x;
    const int j0 = bid * 4;                  // 4 units per layer per block
    const int w = tid >> 6, l = tid & 63;
    const int lb = l & 15, hi4 = l >> 4, xr = l & 7;

    // ---- one-time: stage Whh0/Whh1 slices (16 gate-cols x 1024) hi/lo ----
#pragma unroll
    for (int lay = 0; lay < 2; lay++) {
        const float* Whh = lay ? Whh1 : Whh0;
        char* dH = lay ? W1hi : W0hi;
        char* dL = lay ? W1lo : W0lo;
        for (int i = 0; i < 8; i++) {
            int q = i * 256 + tid;            // 16B chunk id 0..2047
            int row = q >> 7, cin = q & 127;  // row = gate-col (0..15)
            int nrow = (row >> 2) * HIDDEN + j0 + (row & 3);
            const float* src = Whh + (size_t)nrow * HIDDEN + cin * 8;
            int dst = row * 2048 + ((cin ^ (row & 7)) << 4);
            u32 hw[4], lw[4];
#pragma unroll
            for (int e = 0; e < 4; e++) {
                float x0 = src[2 * e], x1 = src[2 * e + 1];
                u32 hb0 = f2bf(x0), hb1 = f2bf(x1);
                hw[e] = hb0 | (hb1 << 16);
                lw[e] = f2bf(x0 - bf2f(hb0)) | (f2bf(x1 - bf2f(hb1)) << 16);
            }
            *(uint4*)(dH + dst) = make_uint4(hw[0], hw[1], hw[2], hw[3]);
            *(uint4*)(dL + dst) = make_uint4(lw[0], lw[1], lw[2], lw[3]);
        }
    }

    // pointwise state (wave 0): lane l -> batch lb, unit jj = hi4 (one per layer)
    float c0r = 0.f, c1r = 0.f;
    float g00 = 0, g01 = 0, g02 = 0, g03 = 0;   // L0 gates (prefetched from G0)
    float g10 = 0, g11 = 0, g12 = 0, g13 = 0;   // L1 gates (constant biases)
    if (tid < 64) {
        c0r = c0in[lb * HIDDEN + j0 + hi4];
        c1r = c0in[16384 + lb * HIDDEN + j0 + hi4];
        const float* gp = G0 + (size_t)lb * GATES + j0 + hi4;   // t = 0
        g00 = gp[0]; g01 = gp[HIDDEN]; g02 = gp[2 * HIDDEN]; g03 = gp[3 * HIDDEN];
        g10 = bi1[j0 + hi4] + bh1[j0 + hi4];
        g11 = bi1[HIDDEN + j0 + hi4] + bh1[HIDDEN + j0 + hi4];
        g12 = bi1[2 * HIDDEN + j0 + hi4] + bh1[2 * HIDDEN + j0 + hi4];
        g13 = bi1[3 * HIDDEN + j0 + hi4] + bh1[3 * HIDDEN + j0 + hi4];
    }
    __syncthreads();

    const u64* s0h = (const u64*)seq0;
    const u64* s0l = (const u64*)(seq0 + SEQ_LOU16);
    const u64* s1h = (const u64*)seq1;
    const u64* s1l = (const u64*)(seq1 + SEQ_LOU16);
    const int fb = lb * 256 + hi4 * 2;            // u64 base within a slot
    const size_t wbase = (size_t)bid * 2048 + l;  // wih fragment entry base

    union u4bf { uint4 u; bf16x8 v; };

    for (int s = 0; s <= SEQ; s++) {
        const bool actL0 = (s < SEQ);
        const bool actL1 = (s >= 1);

        // ---- up-front loads (L2-shared within XCD) ----
        u4bf xh8[8], xl8[8], yh8[8], yl8[8];
        {
            const int base = s * 4096 + fb;
#pragma unroll
            for (int ss = 0; ss < 8; ss++) {
                const int idx = base + (w * 8 + ss) * 8;
                xh8[ss].u = *(const uint4*)(s0h + idx);
                xl8[ss].u = *(const uint4*)(s0l + idx);
            }
        }
        if (actL1) {
            const int base = (s - 1) * 4096 + fb;
#pragma unroll
            for (int ss = 0; ss < 8; ss++) {
                const int idx = base + (w * 8 + ss) * 8;
                yh8[ss].u = *(const uint4*)(s1h + idx);
                yl8[ss].u = *(const uint4*)(s1l + idx);
            }
        }

        if (actL0) {
            f32x4 a0 = {0.f,0.f,0.f,0.f}, a1 = {0.f,0.f,0.f,0.f}, a2 = {0.f,0.f,0.f,0.f};
#pragma unroll
            for (int ss = 0; ss < 8; ss++) {
                const int s32 = w * 8 + ss;
                const int off = lb * 2048 + (((s32 * 4 + hi4) ^ xr) << 4);
                bf16x8 ah = *(const bf16x8*)(W0hi + off);
                bf16x8 al = *(const bf16x8*)(W0lo + off);
                a0 = __builtin_amdgcn_mfma_f32_16x16x32_bf16(ah, xh8[ss].v, a0, 0, 0, 0);
                a1 = __builtin_amdgcn_mfma_f32_16x16x32_bf16(al, xh8[ss].v, a1, 0, 0, 0);
                a2 = __builtin_amdgcn_mfma_f32_16x16x32_bf16(ah, xl8[ss].v, a2, 0, 0, 0);
            }
            f32x4 v0 = a0 + a1 + a2;
            *(f32x4*)&Pw[((0 * 4 + w) * 64 + l) * 4] = v0;
        }

        if (actL1) {
            f32x4 a0 = {0.f,0.f,0.f,0.f}, a1 = {0.f,0.f,0.f,0.f}, a2 = {0.f,0.f,0.f,0.f};
            // input projection: A = pre-swizzled wih frags (L2-resident stream)
#pragma unroll
            for (int ss = 0; ss < 8; ss++) {
                const size_t e = wbase + (size_t)(w * 8 + ss) * 64;
                bf16x8 ah = *(const bf16x8*)(wih_hi + e * 8);
                bf16x8 al = *(const bf16x8*)(wih_lo + e * 8);
                a0 = __builtin_amdgcn_mfma_f32_16x16x32_bf16(ah, xh8[ss].v, a0, 0, 0, 0);
                a1 = __builtin_amdgcn_mfma_f32_16x16x32_bf16(al, xh8[ss].v, a1, 0, 0, 0);
                a2 = __builtin_amdgcn_mfma_f32_16x16x32_bf16(ah, xl8[ss].v, a2, 0, 0, 0);
            }
            // recurrent: A = LDS Whh1
#pragma unroll
            for (int ss = 0; ss < 8; ss++) {
                const int s32 = w * 8 + ss;
                const int off = lb * 2048 + (((s32 * 4 + hi4) ^ xr) << 4);
                bf16x8 ah = *(const bf16x8*)(W1hi + off);
                bf16x8 al = *(const bf16x8*)(W1lo + off);
                a0 = __builtin_amdgcn_mfma_f32_16x16x32_bf16(ah, yh8[ss].v, a0, 0, 0, 0);
                a1 = __builtin_amdgcn_mfma_f32_16x16x32_bf16(al, yh8[ss].v, a1, 0, 0, 0);
                a2 = __builtin_amdgcn_mfma_f32_16x16x32_bf16(ah, yl8[ss].v, a2, 0, 0, 0);
            }
            f32x4 v1 = a0 + a1 + a2;
            *(f32x4*)&Pw[((1 * 4 + w) * 64 + l) * 4] = v1;
        }
        __syncthreads();

        if (tid < 64) {
            // D layout: Pw[(lay*4+w)*64 + ll][jw] = D[c=(ll>>4)*4+jw][b=ll&15].
            if (actL0) {
                float pre[4];
#pragma unroll
                for (int g = 0; g < 4; g++) {
                    const int ll = (g << 4) | lb;
                    pre[g] = Pw[((0 * 4 + 0) * 64 + ll) * 4 + hi4]
                           + Pw[((0 * 4 + 1) * 64 + ll) * 4 + hi4]
                           + Pw[((0 * 4 + 2) * 64 + ll) * 4 + hi4]
                           + Pw[((0 * 4 + 3) * 64 + ll) * 4 + hi4];
                }
                const float ig = 1.f / (1.f + __expf(-(pre[0] + g00)));
                const float fg = 1.f / (1.f + __expf(-(pre[1] + g01)));
                const float gt = tanhf(pre[2] + g02);
                const float og = 1.f / (1.f + __expf(-(pre[3] + g03)));
                c0r = fg * c0r + ig * gt;
                const float hv = og * tanhf(c0r);
                if (s == SEQ - 1) {
                    h_tail[lb * HIDDEN + j0 + hi4] = hv;
                    c_tail[lb * HIDDEN + j0 + hi4] = c0r;
                }
                float q0 = __shfl(hv, 0 + l), q1 = __shfl(hv, 16 + l);
                float q2 = __shfl(hv, 32 + l), q3 = __shfl(hv, 48 + l);
                if (l < 16) {
                    u32 hb0 = f2bf(q0), hb1 = f2bf(q1), hb2 = f2bf(q2), hb3 = f2bf(q3);
                    u64 hq = (u64)(hb0 | (hb1 << 16)) | ((u64)(hb2 | (hb3 << 16)) << 32);
                    u32 lb0 = f2bf(q0 - bf2f(hb0)), lb1 = f2bf(q1 - bf2f(hb1));
                    u32 lb2 = f2bf(q2 - bf2f(hb2)), lb3 = f2bf(q3 - bf2f(hb3));
                    u64 lq = (u64)(lb0 | (lb1 << 16)) | ((u64)(lb2 | (lb3 << 16)) << 32);
                    const int iq = (s + 1) * 4096 + l * 256 + bid;
                    astore((u64*)seq0 + iq, hq);
                    astore((u64*)(seq0 + SEQ_LOU16) + iq, lq);
                }
            }
            if (actL1) {
                float pre[4];
#pragma unroll
                for (int g = 0; g < 4; g++) {
                    const int ll = (g << 4) | lb;
                    pre[g] = Pw[((1 * 4 + 0) * 64 + ll) * 4 + hi4]
                           + Pw[((1 * 4 + 1) * 64 + ll) * 4 + hi4]
                           + Pw[((1 * 4 + 2) * 64 + ll) * 4 + hi4]
                           + Pw[((1 * 4 + 3) * 64 + ll) * 4 + hi4];
                }
                const float ig = 1.f / (1.f + __expf(-(pre[0] + g10)));
                const float fg = 1.f / (1.f + __expf(-(pre[1] + g11)));
                const float gt = tanhf(pre[2] + g12);
                const float og = 1.f / (1.f + __expf(-(pre[3] + g13)));
                c1r = fg * c1r + ig * gt;
                const float hv = og * tanhf(c1r);
                if (s == SEQ) {
                    h_tail[16384 + lb * HIDDEN + j0 + hi4] = hv;
                    c_tail[16384 + lb * HIDDEN + j0 + hi4] = c1r;
                }
                float q0 = __shfl(hv, 0 + l), q1 = __shfl(hv, 16 + l);
                float q2 = __shfl(hv, 32 + l), q3 = __shfl(hv, 48 + l);
                if (l < 16) {
                    u32 hb0 = f2bf(q0), hb1 = f2bf(q1), hb2 = f2bf(q2), hb3 = f2bf(q3);
                    u64 hq = (u64)(hb0 | (hb1 << 16)) | ((u64)(hb2 | (hb3 << 16)) << 32);
                    u32 lb0 = f2bf(q0 - bf2f(hb0)), lb1 = f2bf(q1 - bf2f(hb1));
                    u32 lb2 = f2bf(q2 - bf2f(hb2)), lb3 = f2bf(q3 - bf2f(hb3));
                    u64 lq = (u64)(lb0 | (lb1 << 16)) | ((u64)(lb2 | (lb3 << 16)) << 32);
                    const int iq = s * 4096 + l * 256 + bid;
                    astore((u64*)seq1 + iq, hq);
                    astore((u64*)(seq1 + SEQ_LOU16) + iq, lq);
                }
            }
        }

        if (s < SEQ) {
            if (tid < 64) {
                asm volatile("s_waitcnt vmcnt(0)" ::: "memory");  // drain publishes
                if (tid == 0)
                    __hip_atomic_store(&arrive[bid], (u32)(s + 1), __ATOMIC_RELAXED,
                                       __HIP_MEMORY_SCOPE_AGENT);
                // off critical path: prefetch next step's G0 gates
                if (s + 1 < SEQ) {
                    const float* gp = G0 + (size_t)((s + 1) * BATCH + lb) * GATES + j0 + hi4;
                    g00 = gp[0]; g01 = gp[HIDDEN];
                    g02 = gp[2 * HIDDEN]; g03 = gp[3 * HIDDEN];
                }
                const u32 epoch = (u32)(s + 1);
                const int i0 = l * 4;
                for (;;) {
                    u32 q0 = __hip_atomic_load(&arrive[i0 + 0], __ATOMIC_RELAXED,
                                               __HIP_MEMORY_SCOPE_AGENT);
                    u32 q1 = __hip_atomic_load(&arrive[i0 + 1], __ATOMIC_RELAXED,
                                               __HIP_MEMORY_SCOPE_AGENT);
                    u32 q2 = __hip_atomic_load(&arrive[i0 + 2], __ATOMIC_RELAXED,
                                               __HIP_MEMORY_SCOPE_AGENT);
                    u32 q3 = __hip_atomic_load(&arrive[i0 + 3], __ATOMIC_RELAXED,
                                               __HIP_MEMORY_SCOPE_AGENT);
                    u32 m01 = q0 < q1 ? q0 : q1;
                    u32 m23 = q2 < q3 ? q2 : q3;
                    u32 mn = m01 < m23 ? m01 : m23;
                    if (__all(mn >= epoch)) break;
                    __builtin_amdgcn_s_sleep(2);
                }
                asm volatile("" ::: "memory");   // compiler barrier only
            }
            __syncthreads();
        }
    }
}

// ---------------- init & tails ----------------
__global__ void init_state(const float* __restrict__ h0, u16* __restrict__ seq0,
                           u16* __restrict__ seq1, u32* __restrict__ arrive) {
    int gid = blockIdx.x * 256 + threadIdx.x;  // 32768 = 2*16*1024
    if (gid < 256) arrive[gid] = 0;
    int layer = gid >> 14, b = (gid >> 10) & 15, j = gid & 1023;
    float h = h0[gid];
    u32 hb = f2bf(h);
    u32 lbits = f2bf(h - bf2f(hb));
    u16* sq = layer ? seq1 : seq0;
    sq[b * 1024 + j] = (u16)hb;                 // slot 0 hi
    sq[SEQ_LOU16 + b * 1024 + j] = (u16)lbits;  // slot 0 lo
}

__global__ void write_tails(const float* __restrict__ h_tail, const float* __restrict__ c_tail,
                            float* __restrict__ out) {
    int gid = blockIdx.x * 256 + threadIdx.x;  // 32768
    out[LOGITS_SZ + gid] = h_tail[gid];
    out[LOGITS_SZ + 32768 + gid] = c_tail[gid];
}

// ---------------- launch ----------------
extern "C" void kernel_launch(void* const* d_in, const int* in_sizes, int n_in,
                              void* d_out, int out_size, void* d_ws, size_t ws_size,
                              hipStream_t stream) {
    const int* x = (const int*)d_in[0];
    const float* h0 = (const float*)d_in[1];
    const float* c0 = (const float*)d_in[2];
    const float* emb = (const float*)d_in[3];
    const float* W_ih0 = (const float*)d_in[4];
    const float* W_hh0 = (const float*)d_in[5];
    const float* b_ih0 = (const float*)d_in[6];
    const float* b_hh0 = (const float*)d_in[7];
    const float* W_ih1 = (const float*)d_in[8];
    const float* W_hh1 = (const float*)d_in[9];
    const float* b_ih1 = (const float*)d_in[10];
    const float* b_hh1 = (const float*)d_in[11];
    const float* fc_W = (const float*)d_in[12];
    const float* fc_b = (const float*)d_in[13];
    float* out = (float*)d_out;
    float* ws = (float*)d_ws;

    // workspace layout (float offsets)
    const size_t OFF_G = 0;                                   // G0; later fc_W bf16
    const size_t OFF_X0H = OFF_G + (size_t)MROWS * GATES;     // u16 [4096][512]
    const size_t OFF_X0L = OFF_X0H + (size_t)MROWS * EMBED / 2;
    const size_t OFF_SEQ0 = OFF_X0L + (size_t)MROWS * EMBED / 2;
    const size_t SEQ_FLOATS = (size_t)2 * NSLOT * SEQ_SLOTU16 / 2;
    const size_t OFF_SEQ1 = OFF_SEQ0 + SEQ_FLOATS;
    const size_t OFF_WIHH = OFF_SEQ1 + SEQ_FLOATS;            // wih1 frag-order hi
    const size_t OFF_WIHL = OFF_WIHH + (size_t)GATES * HIDDEN / 2;
    const size_t OFF_W0H = OFF_WIHL + (size_t)GATES * HIDDEN / 2;  // wih0 hi
    const size_t OFF_W0L = OFF_W0H + (size_t)GATES * EMBED / 2;
    const size_t OFF_HT = OFF_W0L + (size_t)GATES * EMBED / 2;
    const size_t OFF_CT = OFF_HT + 2 * BATCH * HIDDEN;
    const size_t OFF_AR = OFF_CT + 2 * BATCH * HIDDEN;

    u16* x0H = (u16*)(ws + OFF_X0H);
    u16* x0L = (u16*)(ws + OFF_X0L);
    u16* seq0 = (u16*)(ws + OFF_SEQ0);
    u16* seq1 = (u16*)(ws + OFF_SEQ1);
    u16* wihH = (u16*)(ws + OFF_WIHH);
    u16* wihL = (u16*)(ws + OFF_WIHL);
    u16* w0H = (u16*)(ws + OFF_W0H);
    u16* w0L = (u16*)(ws + OFF_W0L);
    u32* arrive = (u32*)(ws + OFF_AR);

    init_state<<<128, 256, 0, stream>>>(h0, seq0, seq1, arrive);
    embed_hl_kernel<<<MROWS, 128, 0, stream>>>(x, emb, x0H, x0L);
    wih_swizzle_kernel<<<256, 256, 0, stream>>>(W_ih1, wihH, wihL);
    f32_to_bf16hl_kernel<<<2048, 256, 0, stream>>>(W_ih0, w0H, w0L, GATES * EMBED / 4);

    // layer-0 input projection via split-precision MFMA (includes both L0 biases)
    xproj_mfma<<<dim3(GATES / 128, MROWS / 128), 256, 0, stream>>>(
        x0H, x0L, w0H, w0L, b_ih0, b_hh0, ws + OFF_G);

    // fused balanced pipelined recurrence (both layers) — R11-proven kernel
    {
        const float* Whh0p = W_hh0;
        const float* Whh1p = W_hh1;
        const float* Gp = ws + OFF_G;
        const u16* wh = wihH;
        const u16* wl = wihL;
        const float* bi = b_ih1;
        const float* bh = b_hh1;
        const float* ci = c0;
        float* ct = ws + OFF_CT;
        float* ht = ws + OFF_HT;
        u16* s0 = seq0;
        u16* s1 = seq1;
        u32* ar = arrive;
        void* args[] = {(void*)&Whh0p, (void*)&Whh1p, (void*)&Gp, (void*)&wh,
                        (void*)&wl, (void*)&bi, (void*)&bh, (void*)&ci,
                        (void*)&ct, (void*)&ht, (void*)&s0, (void*)&s1, (void*)&ar};
        hipLaunchCooperativeKernel((void*)lstm_fused, dim3(256), dim3(256), args, 0, stream);
    }

    // FC via bf16 MFMA: A = seq1 hi slots 1..256 directly; B = fc_W bf16 (G0 dead)
    f32_to_bf16_kernel<<<4096, 256, 0, stream>>>(fc_W, (u16*)(ws + OFF_G), VOCAB * HIDDEN / 8);
    fc_mfma<<<dim3(VOCAB / 128, MROWS / 128), 256, 0, stream>>>(
        seq1 + SEQ_SLOTU16, (const u16*)(ws + OFF_G), fc_b, out);

    write_tails<<<128, 256, 0, stream>>>(ws + OFF_HT, ws + OFF_CT, out);
}

// Round 15
// 3780.210 us; speedup vs baseline: 1.0301x; 1.0301x over previous
//
#include <hip/hip_runtime.h>
#include <hip/hip_bf16.h>
#include <cmath>

// Problem constants
#define BATCH 16
#define SEQ 256
#define EMBED 512
#define HIDDEN 1024
#define GATES 4096       // 4*HIDDEN
#define VOCAB 32000
#define MROWS 4096       // BATCH*SEQ
#define LOGITS_SZ 131072000  // 16*256*32000

#define NSLOT 257                    // h-history slots (init + 256 steps)
#define SEQ_SLOTU16 16384            // u16 per slot: 16 batch x 1024
#define SEQ_LOU16 (NSLOT * SEQ_SLOTU16)

typedef unsigned int u32;
typedef unsigned short u16;
typedef unsigned long long u64;
typedef __attribute__((ext_vector_type(8))) short bf16x8;
typedef __attribute__((ext_vector_type(4))) float f32x4;

#define AS1 __attribute__((address_space(1)))
#define AS3 __attribute__((address_space(3)))

// ---------------- helpers ----------------
__device__ __forceinline__ u32 f2bf(float f) {          // RNE fp32->bf16 (bits)
    u32 u = __float_as_uint(f);
    return (u + 0x7fffu + ((u >> 16) & 1u)) >> 16;
}
__device__ __forceinline__ float bf2f(u32 b) { return __uint_as_float(b << 16); }

__device__ __forceinline__ void astore(u64* p, u64 v) {
    __hip_atomic_store(p, v, __ATOMIC_RELAXED, __HIP_MEMORY_SCOPE_AGENT);
}

// ---------------- embedding gather -> bf16 hi/lo planes ----------------
__global__ void embed_hl_kernel(const int* __restrict__ x, const float* __restrict__ emb,
                                u16* __restrict__ XH, u16* __restrict__ XL) {
    int r = blockIdx.x;            // r = s*16 + b
    int s = r >> 4, b = r & 15;
    int tok = x[b * SEQ + s];
    const float4* src = (const float4*)(emb + (size_t)tok * EMBED);
    int i = threadIdx.x;           // 0..127, 4 elems each
    float4 a = src[i];
    u32 h0 = f2bf(a.x), h1 = f2bf(a.y), h2 = f2bf(a.z), h3 = f2bf(a.w);
    u64 hq = (u64)(h0 | (h1 << 16)) | ((u64)(h2 | (h3 << 16)) << 32);
    u32 l0 = f2bf(a.x - bf2f(h0)), l1 = f2bf(a.y - bf2f(h1));
    u32 l2 = f2bf(a.z - bf2f(h2)), l3 = f2bf(a.w - bf2f(h3));
    u64 lq = (u64)(l0 | (l1 << 16)) | ((u64)(l2 | (l3 << 16)) << 32);
    ((u64*)(XH + (size_t)r * EMBED))[i] = hq;
    ((u64*)(XL + (size_t)r * EMBED))[i] = lq;
}

// ---------------- fp32 -> bf16 conversion (hi only, for fc_W) ----------------
__global__ __launch_bounds__(256) void f32_to_bf16_kernel(
    const float* __restrict__ in, u16* __restrict__ out, int n8) {
    for (int i = blockIdx.x * 256 + threadIdx.x; i < n8; i += gridDim.x * 256) {
        float4 a = ((const float4*)in)[2 * (size_t)i + 0];
        float4 b = ((const float4*)in)[2 * (size_t)i + 1];
        uint4 o;
        o.x = f2bf(a.x) | (f2bf(a.y) << 16);
        o.y = f2bf(a.z) | (f2bf(a.w) << 16);
        o.z = f2bf(b.x) | (f2bf(b.y) << 16);
        o.w = f2bf(b.z) | (f2bf(b.w) << 16);
        ((uint4*)out)[i] = o;
    }
}

// ---------------- fp32 -> bf16 hi+lo split ----------------
__global__ __launch_bounds__(256) void f32_to_bf16hl_kernel(
    const float* __restrict__ in, u16* __restrict__ hi, u16* __restrict__ lo, int n4) {
    for (int i = blockIdx.x * 256 + threadIdx.x; i < n4; i += gridDim.x * 256) {
        float4 a = ((const float4*)in)[i];
        u32 h0 = f2bf(a.x), h1 = f2bf(a.y), h2 = f2bf(a.z), h3 = f2bf(a.w);
        u64 hq = (u64)(h0 | (h1 << 16)) | ((u64)(h2 | (h3 << 16)) << 32);
        u32 l0 = f2bf(a.x - bf2f(h0)), l1 = f2bf(a.y - bf2f(h1));
        u32 l2 = f2bf(a.z - bf2f(h2)), l3 = f2bf(a.w - bf2f(h3));
        u64 lq = (u64)(l0 | (l1 << 16)) | ((u64)(l2 | (l3 << 16)) << 32);
        ((u64*)hi)[i] = hq;
        ((u64*)lo)[i] = lq;
    }
}

// ---------------- W_ih1 pre-swizzle into MFMA fragment order ----------------
__global__ __launch_bounds__(256) void wih_swizzle_kernel(
    const float* __restrict__ W, u16* __restrict__ hi, u16* __restrict__ lo) {
    int bid = blockIdx.x, tid = threadIdx.x;
    int j0 = bid * 4;
#pragma unroll
    for (int i = 0; i < 8; i++) {
        int q = i * 256 + tid;           // 0..2047
        int s32 = q >> 6, l = q & 63;
        int row = l & 15, hi4 = l >> 4;
        int nrow = (row >> 2) * HIDDEN + j0 + (row & 3);
        int k = s32 * 32 + hi4 * 8;
        const float* src = W + (size_t)nrow * HIDDEN + k;
        u32 hw[4], lw[4];
#pragma unroll
        for (int e = 0; e < 4; e++) {
            float x0 = src[2 * e], x1 = src[2 * e + 1];
            u32 h0 = f2bf(x0), h1 = f2bf(x1);
            hw[e] = h0 | (h1 << 16);
            lw[e] = f2bf(x0 - bf2f(h0)) | (f2bf(x1 - bf2f(h1)) << 16);
        }
        size_t e0 = (size_t)bid * 2048 + q;
        ((uint4*)hi)[e0] = make_uint4(hw[0], hw[1], hw[2], hw[3]);
        ((uint4*)lo)[e0] = make_uint4(lw[0], lw[1], lw[2], lw[3]);
    }
}

// ---------------- split-precision MFMA input projection (layer 0) ----------
// G0[r][n] = sum_k X[r][k]*Wih0[n][k] + b1[n] + b2[n], via hi/lo 3-chain MFMA.
__global__ __launch_bounds__(256) void xproj_mfma(
    const u16* __restrict__ Ahi, const u16* __restrict__ Alo,   // [MROWS][512]
    const u16* __restrict__ Bhi, const u16* __restrict__ Blo,   // [4096][512]
    const float* __restrict__ b1, const float* __restrict__ b2,
    float* __restrict__ C) {                                    // [MROWS][4096]
    const int K = EMBED;           // 512
    const int N = GATES;
    __shared__ char smem[32768];
    char* AsH = smem;
    char* AsL = smem + 8192;
    char* BsH = smem + 16384;
    char* BsL = smem + 24576;

    int tid = threadIdx.x;
    int w = tid >> 6, l = tid & 63;
    int lin = blockIdx.y * gridDim.x + blockIdx.x;   // [0,1024)
    int swz = (lin & 7) * 128 + (lin >> 3);          // bijective XCD chunks
    int bn = swz % 32, bm = swz / 32;
    int wr = w >> 1, wc = w & 1;
    int lr = l & 15, lk = l >> 4;

    f32x4 acc[4][4];
#pragma unroll
    for (int m = 0; m < 4; m++)
#pragma unroll
        for (int n = 0; n < 4; n++) acc[m][n] = {0.f, 0.f, 0.f, 0.f};

    int srow = tid >> 2, skc = (tid & 3) * 8;
    const u16* gah0 = Ahi + (size_t)(bm * 128 + srow) * K + skc;
    const u16* gah1 = Ahi + (size_t)(bm * 128 + 64 + srow) * K + skc;
    const u16* gal0 = Alo + (size_t)(bm * 128 + srow) * K + skc;
    const u16* gal1 = Alo + (size_t)(bm * 128 + 64 + srow) * K + skc;
    const u16* gbh0 = Bhi + (size_t)(bn * 128 + srow) * K + skc;
    const u16* gbh1 = Bhi + (size_t)(bn * 128 + 64 + srow) * K + skc;
    const u16* gbl0 = Blo + (size_t)(bn * 128 + srow) * K + skc;
    const u16* gbl1 = Blo + (size_t)(bn * 128 + 64 + srow) * K + skc;
    char* lah0 = AsH + w * 1024;       char* lah1 = AsH + 4096 + w * 1024;
    char* lal0 = AsL + w * 1024;       char* lal1 = AsL + 4096 + w * 1024;
    char* lbh0 = BsH + w * 1024;       char* lbh1 = BsH + 4096 + w * 1024;
    char* lbl0 = BsL + w * 1024;       char* lbl1 = BsL + 4096 + w * 1024;

    int afo[4], bfo[4];
#pragma unroll
    for (int m = 0; m < 4; m++) afo[m] = (wr * 64 + m * 16 + lr) * 64 + lk * 16;
#pragma unroll
    for (int n = 0; n < 4; n++) bfo[n] = (wc * 64 + n * 16 + lr) * 64 + lk * 16;

    for (int k0 = 0; k0 < K; k0 += 32) {
        __syncthreads();
        __builtin_amdgcn_global_load_lds((const AS1 u32*)(const void*)(gah0 + k0),
                                         (AS3 u32*)(void*)lah0, 16, 0, 0);
        __builtin_amdgcn_global_load_lds((const AS1 u32*)(const void*)(gah1 + k0),
                                         (AS3 u32*)(void*)lah1, 16, 0, 0);
        __builtin_amdgcn_global_load_lds((const AS1 u32*)(const void*)(gal0 + k0),
                                         (AS3 u32*)(void*)lal0, 16, 0, 0);
        __builtin_amdgcn_global_load_lds((const AS1 u32*)(const void*)(gal1 + k0),
                                         (AS3 u32*)(void*)lal1, 16, 0, 0);
        __builtin_amdgcn_global_load_lds((const AS1 u32*)(const void*)(gbh0 + k0),
                                         (AS3 u32*)(void*)lbh0, 16, 0, 0);
        __builtin_amdgcn_global_load_lds((const AS1 u32*)(const void*)(gbh1 + k0),
                                         (AS3 u32*)(void*)lbh1, 16, 0, 0);
        __builtin_amdgcn_global_load_lds((const AS1 u32*)(const void*)(gbl0 + k0),
                                         (AS3 u32*)(void*)lbl0, 16, 0, 0);
        __builtin_amdgcn_global_load_lds((const AS1 u32*)(const void*)(gbl1 + k0),
                                         (AS3 u32*)(void*)lbl1, 16, 0, 0);
        __syncthreads();

        bf16x8 ah[4], al[4], bh[4], bl[4];
#pragma unroll
        for (int m = 0; m < 4; m++) {
            ah[m] = *(const bf16x8*)(AsH + afo[m]);
            al[m] = *(const bf16x8*)(AsL + afo[m]);
        }
#pragma unroll
        for (int n = 0; n < 4; n++) {
            bh[n] = *(const bf16x8*)(BsH + bfo[n]);
            bl[n] = *(const bf16x8*)(BsL + bfo[n]);
        }
#pragma unroll
        for (int m = 0; m < 4; m++)
#pragma unroll
            for (int n = 0; n < 4; n++) {
                acc[m][n] = __builtin_amdgcn_mfma_f32_16x16x32_bf16(ah[m], bh[n], acc[m][n], 0, 0, 0);
                acc[m][n] = __builtin_amdgcn_mfma_f32_16x16x32_bf16(al[m], bh[n], acc[m][n], 0, 0, 0);
                acc[m][n] = __builtin_amdgcn_mfma_f32_16x16x32_bf16(ah[m], bl[n], acc[m][n], 0, 0, 0);
            }
    }

    int rbase = bm * 128 + wr * 64 + lk * 4;
    int cbase = bn * 128 + wc * 64 + lr;
#pragma unroll
    for (int m = 0; m < 4; m++) {
#pragma unroll
        for (int n = 0; n < 4; n++) {
            int c = cbase + n * 16;
            float bb = b1[c] + b2[c];
#pragma unroll
            for (int j = 0; j < 4; j++) {
                int r = rbase + m * 16 + j;
                C[(size_t)r * N + c] = acc[m][n][j] + bb;
            }
        }
    }
}

// ---------------- bf16 MFMA FC GEMM (XCD-swizzled; R13 scattered epilogue) ---
// R14's LDS-staged coalesced epilogue was NEUTRAL-to-regressive (+58us total):
// the FC is not write-bound (L2 write-combining absorbs the 64B runs). Reverted.
__global__ __launch_bounds__(256) void fc_mfma(
    const u16* __restrict__ Abf,   // [MROWS][1024] bf16
    const u16* __restrict__ Bbf,   // [VOCAB][1024] bf16
    const float* __restrict__ bias,
    float* __restrict__ C) {
    const int K = HIDDEN;
    const int N = VOCAB;
    __shared__ char smem[16384];
    char* As = smem;
    char* Bs = smem + 8192;

    int tid = threadIdx.x;
    int w = tid >> 6, l = tid & 63;
    // XCD-aware bijective swizzle (T1): nwg = 250*32 = 8000, 8000 % 8 == 0.
    int lin = blockIdx.y * gridDim.x + blockIdx.x;
    int swz = (lin & 7) * 1000 + (lin >> 3);
    int bn = swz % 250, bm = swz / 250;
    int wr = w >> 1, wc = w & 1;
    int lr = l & 15, lk = l >> 4;

    f32x4 acc[4][4];
#pragma unroll
    for (int m = 0; m < 4; m++)
#pragma unroll
        for (int n = 0; n < 4; n++) acc[m][n] = {0.f, 0.f, 0.f, 0.f};

    int srow = tid >> 2, skc = (tid & 3) * 8;
    const u16* ga0 = Abf + (size_t)(bm * 128 + srow) * K + skc;
    const u16* ga1 = Abf + (size_t)(bm * 128 + 64 + srow) * K + skc;
    const u16* gb0 = Bbf + (size_t)(bn * 128 + srow) * K + skc;
    const u16* gb1 = Bbf + (size_t)(bn * 128 + 64 + srow) * K + skc;
    char* la0 = As + w * 1024;
    char* la1 = As + 4096 + w * 1024;
    char* lb0 = Bs + w * 1024;
    char* lb1 = Bs + 4096 + w * 1024;

    int afo[4], bfo[4];
#pragma unroll
    for (int m = 0; m < 4; m++) afo[m] = (wr * 64 + m * 16 + lr) * 64 + lk * 16;
#pragma unroll
    for (int n = 0; n < 4; n++) bfo[n] = (wc * 64 + n * 16 + lr) * 64 + lk * 16;

    for (int k0 = 0; k0 < K; k0 += 32) {
        __syncthreads();
        __builtin_amdgcn_global_load_lds((const AS1 u32*)(const void*)(ga0 + k0),
                                         (AS3 u32*)(void*)la0, 16, 0, 0);
        __builtin_amdgcn_global_load_lds((const AS1 u32*)(const void*)(ga1 + k0),
                                         (AS3 u32*)(void*)la1, 16, 0, 0);
        __builtin_amdgcn_global_load_lds((const AS1 u32*)(const void*)(gb0 + k0),
                                         (AS3 u32*)(void*)lb0, 16, 0, 0);
        __builtin_amdgcn_global_load_lds((const AS1 u32*)(const void*)(gb1 + k0),
                                         (AS3 u32*)(void*)lb1, 16, 0, 0);
        __syncthreads();

        bf16x8 af[4], bfr[4];
#pragma unroll
        for (int m = 0; m < 4; m++) af[m] = *(const bf16x8*)(As + afo[m]);
#pragma unroll
        for (int n = 0; n < 4; n++) bfr[n] = *(const bf16x8*)(Bs + bfo[n]);
#pragma unroll
        for (int m = 0; m < 4; m++)
#pragma unroll
            for (int n = 0; n < 4; n++)
                acc[m][n] = __builtin_amdgcn_mfma_f32_16x16x32_bf16(
                    af[m], bfr[n], acc[m][n], 0, 0, 0);
    }

    int rbase = bm * 128 + wr * 64 + lk * 4;
    int cbase = bn * 128 + wc * 64 + lr;
#pragma unroll
    for (int m = 0; m < 4; m++) {
#pragma unroll
        for (int n = 0; n < 4; n++) {
            int c = cbase + n * 16;
            float bb = bias[c];
#pragma unroll
            for (int j = 0; j < 4; j++) {
                int r = rbase + m * 16 + j;
                int orow = (r & 15) * SEQ + (r >> 4);   // [B,S,V] layout
                C[(size_t)orow * N + c] = acc[m][n][j] + bb;
            }
        }
    }
}

// ---------------- fused balanced 2-layer persistent LSTM (R11/R13-proven) ----
// 256 blocks x 256 threads. EVERY block owns 4 L0 units AND 4 L1 units.
// Step s: L0 computes t=s, L1 computes t=s-1; both consume seq0 slot s.
// Whh0/Whh1 hi/lo in LDS; W_ih1 STREAMED from L2 in pre-swizzled fragment
// order (register-resident variant corrupts — R10/R12 bisect; do NOT
// re-attempt). Unified wave-0 tail, single-wave vmcnt->arrive->poll.
__global__ __launch_bounds__(256, 1) void lstm_fused(
    const float* __restrict__ Whh0, const float* __restrict__ Whh1,
    const float* __restrict__ G0,        // [4096][4096] rows t*16+b (L0 x-proj + biases)
    const u16* __restrict__ wih_hi,      // pre-swizzled [256][2048] x 16B
    const u16* __restrict__ wih_lo,
    const float* __restrict__ bi1, const float* __restrict__ bh1,
    const float* __restrict__ c0in,      // [2][16][1024]
    float* __restrict__ c_tail, float* __restrict__ h_tail,  // [2][16][1024]
    u16* __restrict__ seq0, u16* __restrict__ seq1,          // [NSLOT hi | NSLOT lo]
    u32* __restrict__ arrive) {
    __shared__ __align__(16) char lds[139264];
    char* W0hi = lds;                   // [16 rows][2048B] swizzled Whh0 hi
    char* W0lo = lds + 32768;
    char* W1hi = lds + 65536;
    char* W1lo = lds + 98304;
    float* Pw = (float*)(lds + 131072); // [2 layer][4 wave][64 lane][4] = 8 KB

    const int tid = threadIdx.x;
    const int bid = blockIdx.x;
    const int j0 = bid * 4;                  // 4 units per layer per block
    const int w = tid >> 6, l = tid & 63;
    const int lb = l & 15, hi4 = l >> 4, xr = l & 7;

    // ---- one-time: stage Whh0/Whh1 slices (16 gate-cols x 1024) hi/lo ----
#pragma unroll
    for (int lay = 0; lay < 2; lay++) {
        const float* Whh = lay ? Whh1 : Whh0;
        char* dH = lay ? W1hi : W0hi;
        char* dL = lay ? W1lo : W0lo;
        for (int i = 0; i < 8; i++) {
            int q = i * 256 + tid;            // 16B chunk id 0..2047
            int row = q >> 7, cin = q & 127;  // row = gate-col (0..15)
            int nrow = (row >> 2) * HIDDEN + j0 + (row & 3);
            const float* src = Whh + (size_t)nrow * HIDDEN + cin * 8;
            int dst = row * 2048 + ((cin ^ (row & 7)) << 4);
            u32 hw[4], lw[4];
#pragma unroll
            for (int e = 0; e < 4; e++) {
                float x0 = src[2 * e], x1 = src[2 * e + 1];
                u32 hb0 = f2bf(x0), hb1 = f2bf(x1);
                hw[e] = hb0 | (hb1 << 16);
                lw[e] = f2bf(x0 - bf2f(hb0)) | (f2bf(x1 - bf2f(hb1)) << 16);
            }
            *(uint4*)(dH + dst) = make_uint4(hw[0], hw[1], hw[2], hw[3]);
            *(uint4*)(dL + dst) = make_uint4(lw[0], lw[1], lw[2], lw[3]);
        }
    }

    // pointwise state (wave 0): lane l -> batch lb, unit jj = hi4 (one per layer)
    float c0r = 0.f, c1r = 0.f;
    float g00 = 0, g01 = 0, g02 = 0, g03 = 0;   // L0 gates (prefetched from G0)
    float g10 = 0, g11 = 0, g12 = 0, g13 = 0;   // L1 gates (constant biases)
    if (tid < 64) {
        c0r = c0in[lb * HIDDEN + j0 + hi4];
        c1r = c0in[16384 + lb * HIDDEN + j0 + hi4];
        const float* gp = G0 + (size_t)lb * GATES + j0 + hi4;   // t = 0
        g00 = gp[0]; g01 = gp[HIDDEN]; g02 = gp[2 * HIDDEN]; g03 = gp[3 * HIDDEN];
        g10 = bi1[j0 + hi4] + bh1[j0 + hi4];
        g11 = bi1[HIDDEN + j0 + hi4] + bh1[HIDDEN + j0 + hi4];
        g12 = bi1[2 * HIDDEN + j0 + hi4] + bh1[2 * HIDDEN + j0 + hi4];
        g13 = bi1[3 * HIDDEN + j0 + hi4] + bh1[3 * HIDDEN + j0 + hi4];
    }
    __syncthreads();

    const u64* s0h = (const u64*)seq0;
    const u64* s0l = (const u64*)(seq0 + SEQ_LOU16);
    const u64* s1h = (const u64*)seq1;
    const u64* s1l = (const u64*)(seq1 + SEQ_LOU16);
    const int fb = lb * 256 + hi4 * 2;            // u64 base within a slot
    const size_t wbase = (size_t)bid * 2048 + l;  // wih fragment entry base

    union u4bf { uint4 u; bf16x8 v; };

    for (int s = 0; s <= SEQ; s++) {
        const bool actL0 = (s < SEQ);
        const bool actL1 = (s >= 1);

        // ---- up-front loads (L2-shared within XCD) ----
        u4bf xh8[8], xl8[8], yh8[8], yl8[8];
        {
            const int base = s * 4096 + fb;
#pragma unroll
            for (int ss = 0; ss < 8; ss++) {
                const int idx = base + (w * 8 + ss) * 8;
                xh8[ss].u = *(const uint4*)(s0h + idx);
                xl8[ss].u = *(const uint4*)(s0l + idx);
            }
        }
        if (actL1) {
            const int base = (s - 1) * 4096 + fb;
#pragma unroll
            for (int ss = 0; ss < 8; ss++) {
                const int idx = base + (w * 8 + ss) * 8;
                yh8[ss].u = *(const uint4*)(s1h + idx);
                yl8[ss].u = *(const uint4*)(s1l + idx);
            }
        }

        if (actL0) {
            f32x4 a0 = {0.f,0.f,0.f,0.f}, a1 = {0.f,0.f,0.f,0.f}, a2 = {0.f,0.f,0.f,0.f};
#pragma unroll
            for (int ss = 0; ss < 8; ss++) {
                const int s32 = w * 8 + ss;
                const int off = lb * 2048 + (((s32 * 4 + hi4) ^ xr) << 4);
                bf16x8 ah = *(const bf16x8*)(W0hi + off);
                bf16x8 al = *(const bf16x8*)(W0lo + off);
                a0 = __builtin_amdgcn_mfma_f32_16x16x32_bf16(ah, xh8[ss].v, a0, 0, 0, 0);
                a1 = __builtin_amdgcn_mfma_f32_16x16x32_bf16(al, xh8[ss].v, a1, 0, 0, 0);
                a2 = __builtin_amdgcn_mfma_f32_16x16x32_bf16(ah, xl8[ss].v, a2, 0, 0, 0);
            }
            f32x4 v0 = a0 + a1 + a2;
            *(f32x4*)&Pw[((0 * 4 + w) * 64 + l) * 4] = v0;
        }

        if (actL1) {
            f32x4 a0 = {0.f,0.f,0.f,0.f}, a1 = {0.f,0.f,0.f,0.f}, a2 = {0.f,0.f,0.f,0.f};
            // input projection: A = pre-swizzled wih frags (L2-resident stream)
#pragma unroll
            for (int ss = 0; ss < 8; ss++) {
                const size_t e = wbase + (size_t)(w * 8 + ss) * 64;
                bf16x8 ah = *(const bf16x8*)(wih_hi + e * 8);
                bf16x8 al = *(const bf16x8*)(wih_lo + e * 8);
                a0 = __builtin_amdgcn_mfma_f32_16x16x32_bf16(ah, xh8[ss].v, a0, 0, 0, 0);
                a1 = __builtin_amdgcn_mfma_f32_16x16x32_bf16(al, xh8[ss].v, a1, 0, 0, 0);
                a2 = __builtin_amdgcn_mfma_f32_16x16x32_bf16(ah, xl8[ss].v, a2, 0, 0, 0);
            }
            // recurrent: A = LDS Whh1
#pragma unroll
            for (int ss = 0; ss < 8; ss++) {
                const int s32 = w * 8 + ss;
                const int off = lb * 2048 + (((s32 * 4 + hi4) ^ xr) << 4);
                bf16x8 ah = *(const bf16x8*)(W1hi + off);
                bf16x8 al = *(const bf16x8*)(W1lo + off);
                a0 = __builtin_amdgcn_mfma_f32_16x16x32_bf16(ah, yh8[ss].v, a0, 0, 0, 0);
                a1 = __builtin_amdgcn_mfma_f32_16x16x32_bf16(al, yh8[ss].v, a1, 0, 0, 0);
                a2 = __builtin_amdgcn_mfma_f32_16x16x32_bf16(ah, yl8[ss].v, a2, 0, 0, 0);
            }
            f32x4 v1 = a0 + a1 + a2;
            *(f32x4*)&Pw[((1 * 4 + w) * 64 + l) * 4] = v1;
        }
        __syncthreads();

        if (tid < 64) {
            // D layout: Pw[(lay*4+w)*64 + ll][jw] = D[c=(ll>>4)*4+jw][b=ll&15].
            if (actL0) {
                float pre[4];
#pragma unroll
                for (int g = 0; g < 4; g++) {
                    const int ll = (g << 4) | lb;
                    pre[g] = Pw[((0 * 4 + 0) * 64 + ll) * 4 + hi4]
                           + Pw[((0 * 4 + 1) * 64 + ll) * 4 + hi4]
                           + Pw[((0 * 4 + 2) * 64 + ll) * 4 + hi4]
                           + Pw[((0 * 4 + 3) * 64 + ll) * 4 + hi4];
                }
                const float ig = 1.f / (1.f + __expf(-(pre[0] + g00)));
                const float fg = 1.f / (1.f + __expf(-(pre[1] + g01)));
                const float gt = tanhf(pre[2] + g02);
                const float og = 1.f / (1.f + __expf(-(pre[3] + g03)));
                c0r = fg * c0r + ig * gt;
                const float hv = og * tanhf(c0r);
                if (s == SEQ - 1) {
                    h_tail[lb * HIDDEN + j0 + hi4] = hv;
                    c_tail[lb * HIDDEN + j0 + hi4] = c0r;
                }
                float q0 = __shfl(hv, 0 + l), q1 = __shfl(hv, 16 + l);
                float q2 = __shfl(hv, 32 + l), q3 = __shfl(hv, 48 + l);
                if (l < 16) {
                    u32 hb0 = f2bf(q0), hb1 = f2bf(q1), hb2 = f2bf(q2), hb3 = f2bf(q3);
                    u64 hq = (u64)(hb0 | (hb1 << 16)) | ((u64)(hb2 | (hb3 << 16)) << 32);
                    u32 lb0 = f2bf(q0 - bf2f(hb0)), lb1 = f2bf(q1 - bf2f(hb1));
                    u32 lb2 = f2bf(q2 - bf2f(hb2)), lb3 = f2bf(q3 - bf2f(hb3));
                    u64 lq = (u64)(lb0 | (lb1 << 16)) | ((u64)(lb2 | (lb3 << 16)) << 32);
                    const int iq = (s + 1) * 4096 + l * 256 + bid;
                    astore((u64*)seq0 + iq, hq);
                    astore((u64*)(seq0 + SEQ_LOU16) + iq, lq);
                }
            }
            if (actL1) {
                float pre[4];
#pragma unroll
                for (int g = 0; g < 4; g++) {
                    const int ll = (g << 4) | lb;
                    pre[g] = Pw[((1 * 4 + 0) * 64 + ll) * 4 + hi4]
                           + Pw[((1 * 4 + 1) * 64 + ll) * 4 + hi4]
                           + Pw[((1 * 4 + 2) * 64 + ll) * 4 + hi4]
                           + Pw[((1 * 4 + 3) * 64 + ll) * 4 + hi4];
                }
                const float ig = 1.f / (1.f + __expf(-(pre[0] + g10)));
                const float fg = 1.f / (1.f + __expf(-(pre[1] + g11)));
                const float gt = tanhf(pre[2] + g12);
                const float og = 1.f / (1.f + __expf(-(pre[3] + g13)));
                c1r = fg * c1r + ig * gt;
                const float hv = og * tanhf(c1r);
                if (s == SEQ) {
                    h_tail[16384 + lb * HIDDEN + j0 + hi4] = hv;
                    c_tail[16384 + lb * HIDDEN + j0 + hi4] = c1r;
                }
                float q0 = __shfl(hv, 0 + l), q1 = __shfl(hv, 16 + l);
                float q2 = __shfl(hv, 32 + l), q3 = __shfl(hv, 48 + l);
                if (l < 16) {
                    u32 hb0 = f2bf(q0), hb1 = f2bf(q1), hb2 = f2bf(q2), hb3 = f2bf(q3);
                    u64 hq = (u64)(hb0 | (hb1 << 16)) | ((u64)(hb2 | (hb3 << 16)) << 32);
                    u32 lb0 = f2bf(q0 - bf2f(hb0)), lb1 = f2bf(q1 - bf2f(hb1));
                    u32 lb2 = f2bf(q2 - bf2f(hb2)), lb3 = f2bf(q3 - bf2f(hb3));
                    u64 lq = (u64)(lb0 | (lb1 << 16)) | ((u64)(lb2 | (lb3 << 16)) << 32);
                    const int iq = s * 4096 + l * 256 + bid;
                    astore((u64*)seq1 + iq, hq);
                    astore((u64*)(seq1 + SEQ_LOU16) + iq, lq);
                }
            }
        }

        if (s < SEQ) {
            if (tid < 64) {
                asm volatile("s_waitcnt vmcnt(0)" ::: "memory");  // drain publishes
                if (tid == 0)
                    __hip_atomic_store(&arrive[bid], (u32)(s + 1), __ATOMIC_RELAXED,
                                       __HIP_MEMORY_SCOPE_AGENT);
                // off critical path: prefetch next step's G0 gates
                if (s + 1 < SEQ) {
                    const float* gp = G0 + (size_t)((s + 1) * BATCH + lb) * GATES + j0 + hi4;
                    g00 = gp[0]; g01 = gp[HIDDEN];
                    g02 = gp[2 * HIDDEN]; g03 = gp[3 * HIDDEN];
                }
                const u32 epoch = (u32)(s + 1);
                const int i0 = l * 4;
                for (;;) {
                    u32 q0 = __hip_atomic_load(&arrive[i0 + 0], __ATOMIC_RELAXED,
                                               __HIP_MEMORY_SCOPE_AGENT);
                    u32 q1 = __hip_atomic_load(&arrive[i0 + 1], __ATOMIC_RELAXED,
                                               __HIP_MEMORY_SCOPE_AGENT);
                    u32 q2 = __hip_atomic_load(&arrive[i0 + 2], __ATOMIC_RELAXED,
                                               __HIP_MEMORY_SCOPE_AGENT);
                    u32 q3 = __hip_atomic_load(&arrive[i0 + 3], __ATOMIC_RELAXED,
                                               __HIP_MEMORY_SCOPE_AGENT);
                    u32 m01 = q0 < q1 ? q0 : q1;
                    u32 m23 = q2 < q3 ? q2 : q3;
                    u32 mn = m01 < m23 ? m01 : m23;
                    if (__all(mn >= epoch)) break;
                    __builtin_amdgcn_s_sleep(2);
                }
                asm volatile("" ::: "memory");   // compiler barrier only
            }
            __syncthreads();
        }
    }
}

// ---------------- init & tails ----------------
__global__ void init_state(const float* __restrict__ h0, u16* __restrict__ seq0,
                           u16* __restrict__ seq1, u32* __restrict__ arrive) {
    int gid = blockIdx.x * 256 + threadIdx.x;  // 32768 = 2*16*1024
    if (gid < 256) arrive[gid] = 0;
    int layer = gid >> 14, b = (gid >> 10) & 15, j = gid & 1023;
    float h = h0[gid];
    u32 hb = f2bf(h);
    u32 lbits = f2bf(h - bf2f(hb));
    u16* sq = layer ? seq1 : seq0;
    sq[b * 1024 + j] = (u16)hb;                 // slot 0 hi
    sq[SEQ_LOU16 + b * 1024 + j] = (u16)lbits;  // slot 0 lo
}

__global__ void write_tails(const float* __restrict__ h_tail, const float* __restrict__ c_tail,
                            float* __restrict__ out) {
    int gid = blockIdx.x * 256 + threadIdx.x;  // 32768
    out[LOGITS_SZ + gid] = h_tail[gid];
    out[LOGITS_SZ + 32768 + gid] = c_tail[gid];
}

// ---------------- launch ----------------
extern "C" void kernel_launch(void* const* d_in, const int* in_sizes, int n_in,
                              void* d_out, int out_size, void* d_ws, size_t ws_size,
                              hipStream_t stream) {
    const int* x = (const int*)d_in[0];
    const float* h0 = (const float*)d_in[1];
    const float* c0 = (const float*)d_in[2];
    const float* emb = (const float*)d_in[3];
    const float* W_ih0 = (const float*)d_in[4];
    const float* W_hh0 = (const float*)d_in[5];
    const float* b_ih0 = (const float*)d_in[6];
    const float* b_hh0 = (const float*)d_in[7];
    const float* W_ih1 = (const float*)d_in[8];
    const float* W_hh1 = (const float*)d_in[9];
    const float* b_ih1 = (const float*)d_in[10];
    const float* b_hh1 = (const float*)d_in[11];
    const float* fc_W = (const float*)d_in[12];
    const float* fc_b = (const float*)d_in[13];
    float* out = (float*)d_out;
    float* ws = (float*)d_ws;

    // workspace layout (float offsets)
    const size_t OFF_G = 0;                                   // G0; later fc_W bf16
    const size_t OFF_X0H = OFF_G + (size_t)MROWS * GATES;     // u16 [4096][512]
    const size_t OFF_X0L = OFF_X0H + (size_t)MROWS * EMBED / 2;
    const size_t OFF_SEQ0 = OFF_X0L + (size_t)MROWS * EMBED / 2;
    const size_t SEQ_FLOATS = (size_t)2 * NSLOT * SEQ_SLOTU16 / 2;
    const size_t OFF_SEQ1 = OFF_SEQ0 + SEQ_FLOATS;
    const size_t OFF_WIHH = OFF_SEQ1 + SEQ_FLOATS;            // wih1 frag-order hi
    const size_t OFF_WIHL = OFF_WIHH + (size_t)GATES * HIDDEN / 2;
    const size_t OFF_W0H = OFF_WIHL + (size_t)GATES * HIDDEN / 2;  // wih0 hi
    const size_t OFF_W0L = OFF_W0H + (size_t)GATES * EMBED / 2;
    const size_t OFF_HT = OFF_W0L + (size_t)GATES * EMBED / 2;
    const size_t OFF_CT = OFF_HT + 2 * BATCH * HIDDEN;
    const size_t OFF_AR = OFF_CT + 2 * BATCH * HIDDEN;

    u16* x0H = (u16*)(ws + OFF_X0H);
    u16* x0L = (u16*)(ws + OFF_X0L);
    u16* seq0 = (u16*)(ws + OFF_SEQ0);
    u16* seq1 = (u16*)(ws + OFF_SEQ1);
    u16* wihH = (u16*)(ws + OFF_WIHH);
    u16* wihL = (u16*)(ws + OFF_WIHL);
    u16* w0H = (u16*)(ws + OFF_W0H);
    u16* w0L = (u16*)(ws + OFF_W0L);
    u32* arrive = (u32*)(ws + OFF_AR);

    init_state<<<128, 256, 0, stream>>>(h0, seq0, seq1, arrive);
    embed_hl_kernel<<<MROWS, 128, 0, stream>>>(x, emb, x0H, x0L);
    wih_swizzle_kernel<<<256, 256, 0, stream>>>(W_ih1, wihH, wihL);
    f32_to_bf16hl_kernel<<<2048, 256, 0, stream>>>(W_ih0, w0H, w0L, GATES * EMBED / 4);

    // layer-0 input projection via split-precision MFMA (includes both L0 biases)
    xproj_mfma<<<dim3(GATES / 128, MROWS / 128), 256, 0, stream>>>(
        x0H, x0L, w0H, w0L, b_ih0, b_hh0, ws + OFF_G);

    // fused balanced pipelined recurrence (both layers) — R11/R13-proven kernel
    {
        const float* Whh0p = W_hh0;
        const float* Whh1p = W_hh1;
        const float* Gp = ws + OFF_G;
        const u16* wh = wihH;
        const u16* wl = wihL;
        const float* bi = b_ih1;
        const float* bh = b_hh1;
        const float* ci = c0;
        float* ct = ws + OFF_CT;
        float* ht = ws + OFF_HT;
        u16* s0 = seq0;
        u16* s1 = seq1;
        u32* ar = arrive;
        void* args[] = {(void*)&Whh0p, (void*)&Whh1p, (void*)&Gp, (void*)&wh,
                        (void*)&wl, (void*)&bi, (void*)&bh, (void*)&ci,
                        (void*)&ct, (void*)&ht, (void*)&s0, (void*)&s1, (void*)&ar};
        hipLaunchCooperativeKernel((void*)lstm_fused, dim3(256), dim3(256), args, 0, stream);
    }

    // FC via bf16 MFMA: A = seq1 hi slots 1..256 directly; B = fc_W bf16 (G0 dead)
    f32_to_bf16_kernel<<<4096, 256, 0, stream>>>(fc_W, (u16*)(ws + OFF_G), VOCAB * HIDDEN / 8);
    fc_mfma<<<dim3(VOCAB / 128, MROWS / 128), 256, 0, stream>>>(
        seq1 + SEQ_SLOTU16, (const u16*)(ws + OFF_G), fc_b, out);

    write_tails<<<128, 256, 0, stream>>>(ws + OFF_HT, ws + OFF_CT, out);
}